// Round 1
// 541.452 us; speedup vs baseline: 1.0911x; 1.0911x over previous
//
#include <hip/hip_runtime.h>

typedef __attribute__((ext_vector_type(8))) short short8;
typedef __attribute__((ext_vector_type(16))) float f32x16;

#define PL 8256     // lo-plane offset inside a slot
#define SLOT 16448  // hi(8192) + pad(64) + lo(8192)
#define U0O 0
#define U1O SLOT
#define U2O (2 * SLOT)

__device__ __forceinline__ int swadr(int m, int kc) {
  return m * 128 + ((kc ^ (m & 7)) << 4);
}

// one-instruction packed f32->bf16 RNE (no builtin on gfx950; asm per guide)
__device__ __forceinline__ unsigned int cvtpk(float a, float b) {
  unsigned int r;
  asm("v_cvt_pk_bf16_f32 %0, %1, %2" : "=v"(r) : "v"(a), "v"(b));
  return r;
}

__device__ __forceinline__ float dppswap(float v) {  // lane ^ 1
  return __int_as_float(
      __builtin_amdgcn_mov_dpp(__float_as_int(v), 0xB1, 0xF, 0xF, true));
}

__device__ __forceinline__ f32x16 zero16() {
  f32x16 z;
#pragma unroll
  for (int i = 0; i < 16; ++i) z[i] = 0.f;
  return z;
}

// round all 16 lanes-regs to bf16 values in place (RNE), 3 ops / 2 elems
__device__ __forceinline__ void q16x16(f32x16& v) {
#pragma unroll
  for (int r = 0; r < 16; r += 2) {
    unsigned w = cvtpk(v[r], v[r + 1]);
    v[r] = __uint_as_float(w << 16);
    v[r + 1] = __uint_as_float(w & 0xFFFF0000u);
  }
}

// ---- init/pool-phase stores (thread-indexed) ----
__device__ __forceinline__ void store_hi8(char* dst, const float* v) {
  uint4 w = make_uint4(cvtpk(v[0], v[1]), cvtpk(v[2], v[3]),
                       cvtpk(v[4], v[5]), cvtpk(v[6], v[7]));
  *(uint4*)dst = w;
}

__device__ __forceinline__ void split_store8(char* dst, const float* v) {
  unsigned h[4], l[4];
#pragma unroll
  for (int j = 0; j < 4; ++j) {
    unsigned hw = cvtpk(v[2 * j], v[2 * j + 1]);
    float h0 = __uint_as_float(hw << 16);
    float h1 = __uint_as_float(hw & 0xFFFF0000u);
    l[j] = cvtpk(v[2 * j] - h0, v[2 * j + 1] - h1);
    h[j] = hw;
  }
  *(uint4*)dst = make_uint4(h[0], h[1], h[2], h[3]);
  *(uint4*)(dst + PL) = make_uint4(l[0], l[1], l[2], l[3]);
}

__device__ __forceinline__ void split_store4(char* dst, const float* v) {
  unsigned h0 = cvtpk(v[0], v[1]), h1 = cvtpk(v[2], v[3]);
  unsigned l0 = cvtpk(v[0] - __uint_as_float(h0 << 16),
                      v[1] - __uint_as_float(h0 & 0xFFFF0000u));
  unsigned l1 = cvtpk(v[2] - __uint_as_float(h1 << 16),
                      v[3] - __uint_as_float(h1 & 0xFFFF0000u));
  *(uint2*)dst = make_uint2(h0, h1);
  *(uint2*)(dst + PL) = make_uint2(l0, l1);
}

// ---- MFMA macs: precomputed per-lane base pointers, matrix select by imm ----
template <int NK, int OA, int OB>
__device__ __forceinline__ void mac1(f32x16& acc, char* const (&pA)[4],
                                     char* const (&pB)[4]) {
#pragma unroll
  for (int s = 0; s < NK; ++s) {
    short8 a = *(const short8*)(pA[s] + OA);
    short8 b = *(const short8*)(pB[s] + OB);
    acc = __builtin_amdgcn_mfma_f32_32x32x16_bf16(a, b, acc, 0, 0, 0);
  }
}

template <int NK, int OA, int OB>  // A split, B bf16
__device__ __forceinline__ void mac2A(f32x16& acc, char* const (&pA)[4],
                                      char* const (&pB)[4]) {
#pragma unroll
  for (int s = 0; s < NK; ++s) {
    short8 ah = *(const short8*)(pA[s] + OA);
    short8 al = *(const short8*)(pA[s] + OA + PL);
    short8 b = *(const short8*)(pB[s] + OB);
    acc = __builtin_amdgcn_mfma_f32_32x32x16_bf16(ah, b, acc, 0, 0, 0);
    acc = __builtin_amdgcn_mfma_f32_32x32x16_bf16(al, b, acc, 0, 0, 0);
  }
}

template <int NK, int OA, int OB>  // A bf16, B split
__device__ __forceinline__ void mac2B(f32x16& acc, char* const (&pA)[4],
                                      char* const (&pB)[4]) {
#pragma unroll
  for (int s = 0; s < NK; ++s) {
    short8 a = *(const short8*)(pA[s] + OA);
    short8 bh = *(const short8*)(pB[s] + OB);
    short8 bl = *(const short8*)(pB[s] + OB + PL);
    acc = __builtin_amdgcn_mfma_f32_32x32x16_bf16(a, bh, acc, 0, 0, 0);
    acc = __builtin_amdgcn_mfma_f32_32x32x16_bf16(a, bl, acc, 0, 0, 0);
  }
}

template <int NK, int OA, int OB>  // both split (drop lo*lo)
__device__ __forceinline__ void mac3(f32x16& acc, char* const (&pA)[4],
                                     char* const (&pB)[4]) {
#pragma unroll
  for (int s = 0; s < NK; ++s) {
    short8 ah = *(const short8*)(pA[s] + OA);
    short8 al = *(const short8*)(pA[s] + OA + PL);
    short8 bh = *(const short8*)(pB[s] + OB);
    short8 bl = *(const short8*)(pB[s] + OB + PL);
    acc = __builtin_amdgcn_mfma_f32_32x32x16_bf16(ah, bh, acc, 0, 0, 0);
    acc = __builtin_amdgcn_mfma_f32_32x32x16_bf16(ah, bl, acc, 0, 0, 0);
    acc = __builtin_amdgcn_mfma_f32_32x32x16_bf16(al, bh, acc, 0, 0, 0);
  }
}

// ---- C-tile writes: precomputed word offsets, DPP-f32 + cvt_pk packing ----
template <int OFF>
__device__ __forceinline__ void write_hi(char* lds, const int (&wo)[16], bool ev,
                                         const f32x16& vals) {
#pragma unroll
  for (int r = 0; r < 16; ++r) {
    float vn = dppswap(vals[r]);
    unsigned hw = cvtpk(vals[r], vn);  // lo16 = own, hi16 = neighbor
    if (ev) *(unsigned*)(lds + OFF + wo[r]) = hw;
  }
}

template <int OFF>
__device__ __forceinline__ void write_split(char* lds, const int (&wo)[16],
                                            bool ev, int pl, const f32x16& vals,
                                            int r0, int r1) {
#pragma unroll
  for (int r = 0; r < 16; ++r) {
    if (r < r0 || r >= r1) continue;
    float v = vals[r];
    float vn = dppswap(v);
    unsigned hw = cvtpk(v, vn);              // even-lane hi word
    float lo = v - __uint_as_float(hw << 16);  // exact residual vs own hi
    float lon = dppswap(lo);
    unsigned lw = cvtpk(lon, lo);            // odd-lane lo word
    *(unsigned*)(lds + OFF + pl + wo[r]) = ev ? hw : lw;
  }
}

__global__ void __launch_bounds__(256, 3)
spd_pool_kernel(const float* __restrict__ X, float* __restrict__ out) {
  __shared__ __align__(16) char lds[3 * SLOT];

  const int tid = threadIdx.x;
  const int lane = tid & 63;
  const int wv = tid >> 6;
  const int R = (wv >> 1) * 32;
  const int Cc = (wv & 1) * 32;
  const int half = lane >> 5;
  const int ln31 = lane & 31;
  const bool ev = (ln31 & 1) == 0;
  const int pl = ev ? 0 : PL;

  // per-lane ds read base pointers (row + swizzled chunk); matrix via imm OFF
  char* pA[4];
  char* pB[4];
#pragma unroll
  for (int s = 0; s < 4; ++s) {
    const int kc = 2 * s + half;
    pA[s] = lds + swadr(R + ln31, kc);
    pB[s] = lds + swadr(Cc + ln31, kc);
  }

  // per-lane C-write word offsets (fixed for all 64x64 phases)
  int wo[16];
  {
    const int col0 = Cc + (ln31 & ~1);
    const int cchunk = col0 >> 3, cbyte = (col0 & 7) * 2;
    const int rbase = R + 4 * half;
#pragma unroll
    for (int r = 0; r < 16; ++r) {
      const int m = rbase + (r & 3) + 8 * (r >> 2);
      wo[r] = m * 128 + ((cchunk ^ (m & 7)) << 4) + cbyte;
    }
  }

  // diagonal mask of this thread's C fragment (fixed)
  f32x16 dmask;
#pragma unroll
  for (int r = 0; r < 16; ++r)
    dmask[r] = (R + (r & 3) + 8 * (r >> 2) + 4 * half == Cc + ln31) ? 1.f : 0.f;

  f32x16 mY, mZ;

  // ======= init: U0 = X' = X/6.6 (split); U1h = T0 =======
  {
    const int em = tid >> 2;
    const int ekc = (tid & 3) * 2;
    const int ec0 = ekc * 8;
    const float ic1 = 1.0f / 6.6f;
    const float* Xg = X + (size_t)blockIdx.x * 4096 + em * 64 + ec0;
    const float4* xp = (const float4*)Xg;
    float4 a = xp[0], b = xp[1], c = xp[2], d = xp[3];
    float v[16] = {a.x * ic1, a.y * ic1, a.z * ic1, a.w * ic1,
                   b.x * ic1, b.y * ic1, b.z * ic1, b.w * ic1,
                   c.x * ic1, c.y * ic1, c.z * ic1, c.w * ic1,
                   d.x * ic1, d.y * ic1, d.z * ic1, d.w * ic1};
    float t[16];
#pragma unroll
    for (int i = 0; i < 16; ++i)
      t[i] = ((em == ec0 + i) ? 1.5f : 0.f) - 0.5f * v[i];
    split_store8(lds + swadr(em, ekc), v);
    split_store8(lds + swadr(em, ekc + 1), v + 8);
    store_hi8(lds + U1O + swadr(em, ekc), t);
    store_hi8(lds + U1O + swadr(em, ekc + 1), t + 8);
  }
  __syncthreads();
  // L1 iter1: Y = X'h * T0 -> U2h
  mY = zero16();
  mac1<4, U0O, U1O>(mY, pA, pB);
  write_hi<U2O>(lds, wo, ev, mY);
  __syncthreads();
  // L1 bf16 iters 2..5 (Y=U2h, Z=U1h, T=U2l)
#pragma unroll 1
  for (int it = 0; it < 4; ++it) {
    f32x16 a;
#pragma unroll
    for (int r = 0; r < 16; ++r) a[r] = -3.f * dmask[r];  // preload -3I
    mac1<4, U1O, U2O>(a, pA, pB);
    f32x16 tv;
#pragma unroll
    for (int r = 0; r < 16; ++r) tv[r] = -0.5f * a[r];  // T = 1.5I - 0.5 ZY
    write_hi<U2O + PL>(lds, wo, ev, tv);
    __syncthreads();
    mY = zero16();
    mac1<4, U2O, U2O + PL>(mY, pA, pB);
    mZ = zero16();
    mac1<4, U2O + PL, U1O>(mZ, pA, pB);
    __syncthreads();
    write_hi<U2O>(lds, wo, ev, mY);
    write_hi<U1O>(lds, wo, ev, mZ);
    __syncthreads();
  }
  // L1 restore: mY = X' * Zh -> split U2   (reg mZ dead until L2 -> no q16)
  mY = zero16();
  mac2A<4, U0O, U1O>(mY, pA, pB);
  write_split<U2O>(lds, wo, ev, pl, mY, 0, 16);
  __syncthreads();
  // L1 delta iter (Y only): D = 0.5(I - Zh*Y) -> U0h
  {
    f32x16 a;
#pragma unroll
    for (int r = 0; r < 16; ++r) a[r] = -dmask[r];  // preload -I
    mac2B<4, U1O, U2O>(a, pA, pB);
    f32x16 dv;
#pragma unroll
    for (int r = 0; r < 16; ++r) dv[r] = -0.5f * a[r];
    write_hi<U0O>(lds, wo, ev, dv);
  }
  __syncthreads();
  mac1<4, U2O, U0O>(mY, pA, pB);  // mY += Yh*D
  __syncthreads();
  write_split<U2O>(lds, wo, ev, pl, mY, 0, 16);  // X2' = Y1 (split)
  // L2 T0 from mY (regs)
  {
    f32x16 t0v;
#pragma unroll
    for (int r = 0; r < 16; ++r) t0v[r] = 1.5f * dmask[r] - 0.5f * mY[r];
    write_hi<U1O>(lds, wo, ev, t0v);
  }
  __syncthreads();
  // L2 iter1: Y = X2'h * T0 -> U0h
  mY = zero16();
  mac1<4, U2O, U1O>(mY, pA, pB);
  write_hi<U0O>(lds, wo, ev, mY);
  __syncthreads();
  // L2 bf16 iters 2..3 (Y=U0h, Z=U1h, T=U0l)
#pragma unroll 1
  for (int it = 0; it < 2; ++it) {
    f32x16 a;
#pragma unroll
    for (int r = 0; r < 16; ++r) a[r] = -3.f * dmask[r];
    mac1<4, U1O, U0O>(a, pA, pB);
    f32x16 tv;
#pragma unroll
    for (int r = 0; r < 16; ++r) tv[r] = -0.5f * a[r];
    write_hi<U0O + PL>(lds, wo, ev, tv);
    __syncthreads();
    mY = zero16();
    mac1<4, U0O, U0O + PL>(mY, pA, pB);
    mZ = zero16();
    mac1<4, U0O + PL, U1O>(mZ, pA, pB);
    __syncthreads();
    write_hi<U0O>(lds, wo, ev, mY);
    write_hi<U1O>(lds, wo, ev, mZ);
    __syncthreads();
  }
  // L2 restore
  q16x16(mZ);  // master Z matches stored bf16
  mY = zero16();
  mac2A<4, U2O, U1O>(mY, pA, pB);
  write_split<U0O>(lds, wo, ev, pl, mY, 0, 16);
  __syncthreads();
  // L2 delta4
  {
    f32x16 a;
#pragma unroll
    for (int r = 0; r < 16; ++r) a[r] = -dmask[r];
    mac2B<4, U1O, U0O>(a, pA, pB);
    f32x16 dv;
#pragma unroll
    for (int r = 0; r < 16; ++r) dv[r] = -0.5f * a[r];
    write_hi<U2O>(lds, wo, ev, dv);  // D (X2' dead)
  }
  __syncthreads();
  mac1<4, U0O, U2O>(mY, pA, pB);  // mY += Yh*D
  mac1<4, U2O, U1O>(mZ, pA, pB);  // mZ += D*Zh
  __syncthreads();
  write_split<U0O>(lds, wo, ev, pl, mY, 0, 16);
  q16x16(mZ);
  write_hi<U1O>(lds, wo, ev, mZ);
  __syncthreads();
  // L2 delta5 (masters final, no writeback)
  {
    f32x16 a;
#pragma unroll
    for (int r = 0; r < 16; ++r) a[r] = -dmask[r];
    mac2B<4, U1O, U0O>(a, pA, pB);
    f32x16 dv;
#pragma unroll
    for (int r = 0; r < 16; ++r) dv[r] = -0.5f * a[r];
    write_hi<U2O>(lds, wo, ev, dv);
  }
  __syncthreads();
  mac1<4, U0O, U2O>(mY, pA, pB);
  mac1<4, U2O, U1O>(mZ, pA, pB);
  // S = ca*Y2 - cb*Z2 -> split U0
  f32x16 sv;
  {
    const float ca = 0.80141224f;  // 6.6^{1/4}/2
    const float cb = 0.31194493f;  // 1/(2*6.6^{1/4})
#pragma unroll
    for (int r = 0; r < 16; ++r) sv[r] = ca * mY[r] - cb * mZ[r];
  }
  __syncthreads();
  write_split<U0O>(lds, wo, ev, pl, sv, 0, 16);
  __syncthreads();
  // S2 = S*S; S2h -> U1h; q init -> U1l
  {
    f32x16 s2 = zero16();
    mac3<4, U0O, U0O>(s2, pA, pB);
    const float A11 = -0.08948864f, A9 = 0.12152778f;
    f32x16 qv;
#pragma unroll
    for (int r = 0; r < 16; ++r) qv[r] = A11 * s2[r] + A9 * dmask[r];
    write_hi<U1O>(lds, wo, ev, s2);
    write_hi<U1O + PL>(lds, wo, ev, qv);
  }
  __syncthreads();
  // asinh Horner (bf16): 3 steps — epilogue folded into acc preload
  {
    const float acoef[3] = {-0.17857143f, 0.3f, -0.66666667f};
#pragma unroll 1
    for (int j = 0; j < 3; ++j) {
      f32x16 a;
#pragma unroll
      for (int r = 0; r < 16; ++r) a[r] = acoef[j] * dmask[r];
      mac1<4, U1O + PL, U1O>(a, pA, pB);
      __syncthreads();
      write_hi<U1O + PL>(lds, wo, ev, a);
      __syncthreads();
    }
  }
  // last q step: q4 = q*S2 + 4I -> split U2
  {
    f32x16 a;
#pragma unroll
    for (int r = 0; r < 16; ++r) a[r] = 4.f * dmask[r];
    mac1<4, U1O + PL, U1O>(a, pA, pB);
    __syncthreads();
    write_split<U2O>(lds, wo, ev, pl, a, 0, 16);
    __syncthreads();
  }
  // L = S*q4 -> raw f32 row-major into U1 region
  {
    f32x16 mL = zero16();
    mac3<4, U0O, U2O>(mL, pA, pB);
    float* Lf = (float*)(lds + U1O);
#pragma unroll
    for (int r = 0; r < 16; ++r)
      Lf[(R + (r & 3) + 8 * (r >> 2) + 4 * half) * 64 + Cc + ln31] = mL[r];
  }
  __syncthreads();
  // pool -> P2 = P/2 (split, U0 rows 0..31); q2 init -> U2
  {
    const float d8 = 2.4801587e-5f, d7 = 1.9841270e-4f;
    const float* Lf = (const float*)(lds + U1O);
    int i = tid >> 3, ct = tid & 7, j4 = ct * 4;
    const float4* r0p = (const float4*)&Lf[(2 * i) * 64 + 8 * ct];
    const float4* r1p = (const float4*)&Lf[(2 * i + 1) * 64 + 8 * ct];
    float4 a0 = r0p[0], a1 = r0p[1], b0 = r1p[0], b1 = r1p[1];
    float p[4], q2v[4];
    p[0] = 0.125f * (a0.x + a0.y + b0.x + b0.y);
    p[1] = 0.125f * (a0.z + a0.w + b0.z + b0.w);
    p[2] = 0.125f * (a1.x + a1.y + b1.x + b1.y);
    p[3] = 0.125f * (a1.z + a1.w + b1.z + b1.w);
#pragma unroll
    for (int qq = 0; qq < 4; ++qq)
      q2v[qq] = d8 * p[qq] + ((i == j4 + qq) ? d7 : 0.f);
    int boff = swadr(i, ct >> 1) + (j4 & 7) * 2;
    split_store4(lds + boff, p);
    split_store4(lds + U2O + boff, q2v);
  }
  __syncthreads();
  // exp-phase per-lane setup (32x32 role: rows = ln31)
  char* pE[4];
#pragma unroll
  for (int s = 0; s < 4; ++s) pE[s] = lds + swadr(ln31, 2 * s + half);
  f32x16 dmask2;
#pragma unroll
  for (int r = 0; r < 16; ++r)
    dmask2[r] = ((r & 3) + 8 * (r >> 2) + 4 * half == ln31) ? 1.f : 0.f;
  int wo2[16];
  {
    const int col0 = ln31 & ~1;
    const int cchunk = col0 >> 3, cbyte = (col0 & 7) * 2;
    const int rbase = 4 * half;
#pragma unroll
    for (int r = 0; r < 16; ++r) {
      const int m = rbase + (r & 3) + 8 * (r >> 2);
      wo2[r] = m * 128 + ((cchunk ^ (m & 7)) << 4) + cbyte;
    }
  }
  // exp(P/2) Horner: 7 in-place steps on U2 (32x32)
  {
    const float dcoef[7] = {1.f / 720.f, 1.f / 120.f, 1.f / 24.f,
                            1.f / 6.f,   0.5f,        1.f,       1.f};
#pragma unroll 1
    for (int j = 0; j < 7; ++j) {
      f32x16 acc;
#pragma unroll
      for (int r = 0; r < 16; ++r) acc[r] = dcoef[j] * dmask2[r];  // preload
      mac3<2, U2O, U0O>(acc, pE, pE);
      __syncthreads();
      write_split<U2O>(lds, wo2, ev, pl, acc, 4 * wv, 4 * wv + 4);
      __syncthreads();
    }
  }
  // OUT = H*H -> global fp32
  {
    f32x16 acc = zero16();
    mac3<2, U2O, U2O>(acc, pE, pE);
    float* og = out + (size_t)blockIdx.x * 1024;
#pragma unroll
    for (int r = 0; r < 16; ++r) {
      if (r < 4 * wv || r >= 4 * wv + 4) continue;
      int rl = (r & 3) + 8 * (r >> 2) + 4 * half;
      og[rl * 32 + ln31] = acc[r];
    }
  }
}

extern "C" void kernel_launch(void* const* d_in, const int* in_sizes, int n_in,
                              void* d_out, int out_size, void* d_ws, size_t ws_size,
                              hipStream_t stream) {
  const float* X = (const float*)d_in[0];
  float* out = (float*)d_out;
  const int batch = in_sizes[0] / 4096;  // 8192
  spd_pool_kernel<<<batch, 256, 0, stream>>>(X, out);
}